// Round 2
// baseline (1086.267 us; speedup 1.0000x reference)
//
#include <hip/hip_runtime.h>
#include <hip/hip_bf16.h>

#define N_NODESC 50000
#define N_EDGESC 800000
#define E_TOTC   850000   // + self loops
#define IN_DIMC  128
#define FDIM     256      // HEADS*HID
#define HEADSC   4
#define HIDC     64
#define NEG_SLOPE 0.2f

__device__ __forceinline__ float wave_sum(float v){
  #pragma unroll
  for (int m = 32; m > 0; m >>= 1) v += __shfl_xor(v, m, 64);
  return v;
}
__device__ __forceinline__ float wave_max(float v){
  #pragma unroll
  for (int m = 32; m > 0; m >>= 1) v = fmaxf(v, __shfl_xor(v, m, 64));
  return v;
}

// ---------- edge_attr column means (for self-loop fill) ----------
__global__ __launch_bounds__(256) void k_mean(const float* __restrict__ ea,
                                              float* __restrict__ meanacc){
  float s0 = 0.f, s1 = 0.f, s2 = 0.f;
  for (int i = blockIdx.x * blockDim.x + threadIdx.x; i < N_EDGESC;
       i += gridDim.x * blockDim.x){
    s0 += ea[i*3+0]; s1 += ea[i*3+1]; s2 += ea[i*3+2];
  }
  s0 = wave_sum(s0); s1 = wave_sum(s1); s2 = wave_sum(s2);
  __shared__ float red[3][4];
  int lane = threadIdx.x & 63, w = threadIdx.x >> 6;
  if (lane == 0){ red[0][w] = s0; red[1][w] = s1; red[2][w] = s2; }
  __syncthreads();
  if (threadIdx.x == 0){
    float t0 = 0.f, t1 = 0.f, t2 = 0.f;
    for (int i = 0; i < 4; i++){ t0 += red[0][i]; t1 += red[1][i]; t2 += red[2][i]; }
    atomicAdd(&meanacc[0], t0); atomicAdd(&meanacc[1], t1); atomicAdd(&meanacc[2], t2);
  }
}

// ---------- layer-1 dual GEMM: xl = x@W1l, xr = x@W1r (fp32 out) ----------
__global__ __launch_bounds__(256) void k_gemm1(const float* __restrict__ x,
                                               const float* __restrict__ Wl,
                                               const float* __restrict__ Wr,
                                               float* __restrict__ xl,
                                               float* __restrict__ xr){
  __shared__ float xs[8][IN_DIMC];
  const int r0 = blockIdx.x * 8;
  const int t = threadIdx.x;
  for (int i = t; i < 8 * IN_DIMC; i += 256){
    int r = i >> 7, k = i & 127;
    xs[r][k] = x[(size_t)(r0 + r) * IN_DIMC + k];
  }
  __syncthreads();
  float accl[8] = {0,0,0,0,0,0,0,0};
  float accr[8] = {0,0,0,0,0,0,0,0};
  for (int k = 0; k < IN_DIMC; k++){
    float wl = Wl[k * FDIM + t];
    float wr = Wr[k * FDIM + t];
    #pragma unroll
    for (int r = 0; r < 8; r++){ accl[r] += xs[r][k] * wl; accr[r] += xs[r][k] * wr; }
  }
  #pragma unroll
  for (int r = 0; r < 8; r++){
    xl[(size_t)(r0 + r) * FDIM + t] = accl[r];
    xr[(size_t)(r0 + r) * FDIM + t] = accr[r];
  }
}

// ---------- CSR build: count, scan, scatter ----------
__global__ __launch_bounds__(256) void k_count(const int* __restrict__ ei,
                                               int* __restrict__ deg){
  int e = blockIdx.x * blockDim.x + threadIdx.x;
  if (e >= E_TOTC) return;
  int dst = (e < N_EDGESC) ? ei[N_EDGESC + e] : (e - N_EDGESC);
  atomicAdd(&deg[dst], 1);
}

__global__ __launch_bounds__(1024) void k_scan(const int* __restrict__ deg,
                                               int* __restrict__ offsets,
                                               int* __restrict__ cursor){
  const int n = N_NODESC;
  const int T = 1024;
  const int CH = (n + T - 1) / T;
  int t = threadIdx.x;
  int beg = t * CH, end = min(beg + CH, n);
  int s = 0;
  for (int i = beg; i < end; i++) s += deg[i];
  __shared__ int sums[1024];
  sums[t] = s;
  __syncthreads();
  for (int off = 1; off < T; off <<= 1){
    int v = (t >= off) ? sums[t - off] : 0;
    __syncthreads();
    sums[t] += v;
    __syncthreads();
  }
  int run = sums[t] - s;             // exclusive prefix
  for (int i = beg; i < end; i++){
    offsets[i] = run; cursor[i] = run; run += deg[i];
  }
  if (t == T - 1) offsets[n] = sums[T - 1];
}

__global__ __launch_bounds__(256) void k_scatter(const int* __restrict__ ei,
                                                 int* __restrict__ cursor,
                                                 int* __restrict__ perm){
  int e = blockIdx.x * blockDim.x + threadIdx.x;
  if (e >= E_TOTC) return;
  int dst = (e < N_EDGESC) ? ei[N_EDGESC + e] : (e - N_EDGESC);
  int pos = atomicAdd(&cursor[dst], 1);
  perm[pos] = e;
}

// ---------- layer-1 edge logits (one wave per permuted edge) ----------
__global__ __launch_bounds__(256) void k_logits1(const int* __restrict__ ei,
                                                 const float* __restrict__ ea,
                                                 const float* __restrict__ W1e,
                                                 const float* __restrict__ att1,
                                                 const float* __restrict__ meanacc,
                                                 const int* __restrict__ perm,
                                                 const float* __restrict__ xl,
                                                 const float* __restrict__ xr,
                                                 float* __restrict__ logits,
                                                 int* __restrict__ srcp){
  __shared__ float w1e_s[3 * FDIM];
  __shared__ float att_s[FDIM];
  int t = threadIdx.x;
  for (int i = t; i < 3 * FDIM; i += 256) w1e_s[i] = W1e[i];
  for (int i = t; i < FDIM; i += 256)     att_s[i] = att1[i];
  __syncthreads();
  int j = blockIdx.x * 4 + (t >> 6);
  if (j >= E_TOTC) return;
  int lane = t & 63;
  int e = perm[j];
  int src, dst; float e0, e1, e2;
  if (e < N_EDGESC){
    src = ei[e]; dst = ei[N_EDGESC + e];
    e0 = ea[e*3+0]; e1 = ea[e*3+1]; e2 = ea[e*3+2];
  } else {
    src = dst = e - N_EDGESC;
    const float inv = 1.0f / (float)N_EDGESC;
    e0 = meanacc[0]*inv; e1 = meanacc[1]*inv; e2 = meanacc[2]*inv;
  }
  const float* xls = xl + (size_t)src * FDIM;
  const float* xrs = xr + (size_t)dst * FDIM;
  #pragma unroll
  for (int h = 0; h < HEADSC; h++){
    int idx = h * HIDC + lane;
    float ef = e0*w1e_s[idx] + e1*w1e_s[FDIM+idx] + e2*w1e_s[2*FDIM+idx];
    float v  = xls[idx] + xrs[idx] + ef;
    v = (v > 0.f) ? v : NEG_SLOPE * v;
    float p = v * att_s[idx];
    p = wave_sum(p);
    if (lane == 0) logits[(size_t)j * 4 + h] = p;
  }
  if (lane == 0) srcp[j] = src;
}

// ---------- layer-1: segment softmax + aggregation + ELU + fused layer-2 dots ----------
__global__ __launch_bounds__(256) void k_node1(const int* __restrict__ offsets,
                                               const int* __restrict__ srcp,
                                               const float* __restrict__ logits,
                                               const float* __restrict__ xl,
                                               const float* __restrict__ b1,
                                               const float* __restrict__ W2l,
                                               const float* __restrict__ W2r,
                                               float* __restrict__ sl,
                                               float* __restrict__ sr){
  int n = blockIdx.x;
  int beg = offsets[n], end = offsets[n + 1];
  int t = threadIdx.x, lane = t & 63, w = t >> 6;
  __shared__ float mx_s[4], den_s[4];
  {
    float m = -1e30f;
    for (int j = beg + lane; j < end; j += 64)
      m = fmaxf(m, logits[(size_t)j * 4 + w]);
    m = wave_max(m);
    float s = 0.f;
    for (int j = beg + lane; j < end; j += 64)
      s += expf(logits[(size_t)j * 4 + w] - m);
    s = wave_sum(s);
    if (lane == 0){ mx_s[w] = m; den_s[w] = s; }
  }
  __syncthreads();
  __shared__ float alpha_s[4][64];
  __shared__ int   src_s[64];
  float acc = 0.f;
  for (int chunk = beg; chunk < end; chunk += 64){
    int cnt = min(64, end - chunk);
    if (lane < cnt){
      if (w == 0) src_s[lane] = srcp[chunk + lane];
      alpha_s[w][lane] = expf(logits[(size_t)(chunk + lane) * 4 + w] - mx_s[w]) / den_s[w];
    }
    __syncthreads();
    for (int i = 0; i < cnt; i++)
      acc += alpha_s[w][i] * xl[(size_t)src_s[i] * FDIM + t];
    __syncthreads();
  }
  // h[n][t]
  float v = acc + b1[t];
  v = (v > 0.f) ? v : (expf(v) - 1.f);   // ELU
  // fused layer-2 per-node dots: sl = h.W2l, sr = h.W2r (block reduction)
  float a = v * W2l[t];
  float b = v * W2r[t];
  a = wave_sum(a); b = wave_sum(b);
  __shared__ float sred[2][4];
  if (lane == 0){ sred[0][w] = a; sred[1][w] = b; }
  __syncthreads();
  if (t == 0){
    float sa = 0.f, sb = 0.f;
    for (int i = 0; i < 4; i++){ sa += sred[0][i]; sb += sred[1][i]; }
    sl[n] = sa; sr[n] = sb;
  }
}

// ---------- layer-2 edge logits ----------
__global__ __launch_bounds__(256) void k_logits2(const int* __restrict__ ei,
                                                 const float* __restrict__ ea,
                                                 const float* __restrict__ W2e,
                                                 const float* __restrict__ att2,
                                                 const float* __restrict__ meanacc,
                                                 const int* __restrict__ perm,
                                                 const int* __restrict__ srcp,
                                                 const float* __restrict__ sl,
                                                 const float* __restrict__ sr,
                                                 float* __restrict__ lg2){
  int j = blockIdx.x * blockDim.x + threadIdx.x;
  if (j >= E_TOTC) return;
  int e = perm[j];
  int dst; float e0, e1, e2;
  if (e < N_EDGESC){
    dst = ei[N_EDGESC + e];
    e0 = ea[e*3+0]; e1 = ea[e*3+1]; e2 = ea[e*3+2];
  } else {
    dst = e - N_EDGESC;
    const float inv = 1.0f / (float)N_EDGESC;
    e0 = meanacc[0]*inv; e1 = meanacc[1]*inv; e2 = meanacc[2]*inv;
  }
  float ef = e0*W2e[0] + e1*W2e[1] + e2*W2e[2];
  float v = sl[srcp[j]] + sr[dst] + ef;
  v = (v > 0.f) ? v : NEG_SLOPE * v;
  lg2[j] = v * att2[0];
}

// ---------- layer-2 per-node softmax + aggregate -> scores ----------
__global__ __launch_bounds__(256) void k_node2(const int* __restrict__ offsets,
                                               const int* __restrict__ srcp,
                                               const float* __restrict__ lg2,
                                               const float* __restrict__ sl,
                                               const float* __restrict__ b2p,
                                               float* __restrict__ scores,
                                               float* __restrict__ out){
  int t = threadIdx.x, lane = t & 63;
  int n = blockIdx.x * 4 + (t >> 6);
  if (n >= N_NODESC) return;
  int beg = offsets[n], end = offsets[n + 1];
  float m = -1e30f;
  for (int j = beg + lane; j < end; j += 64) m = fmaxf(m, lg2[j]);
  m = wave_max(m);
  float den = 0.f, num = 0.f;
  for (int j = beg + lane; j < end; j += 64){
    float a = expf(lg2[j] - m);
    den += a;
    num += a * sl[srcp[j]];
  }
  den = wave_sum(den); num = wave_sum(num);
  if (lane == 0){
    float s = num / den + b2p[0];
    scores[n] = s;
    out[N_NODESC + n] = s;
  }
}

// ---------- global softmax over scores ----------
__device__ __forceinline__ unsigned fkey(float f){
  unsigned u = __float_as_uint(f);
  return u ^ ((u >> 31) ? 0xFFFFFFFFu : 0x80000000u);
}
__device__ __forceinline__ float funkey(unsigned k){
  unsigned u = (k >> 31) ? (k ^ 0x80000000u) : ~k;
  return __uint_as_float(u);
}

__global__ __launch_bounds__(256) void k_smax_max(const float* __restrict__ scores,
                                                  unsigned* __restrict__ redmax){
  float m = -1e30f;
  for (int i = blockIdx.x * blockDim.x + threadIdx.x; i < N_NODESC;
       i += gridDim.x * blockDim.x)
    m = fmaxf(m, scores[i]);
  m = wave_max(m);
  __shared__ float ws_[4];
  int lane = threadIdx.x & 63, w = threadIdx.x >> 6;
  if (lane == 0) ws_[w] = m;
  __syncthreads();
  if (threadIdx.x == 0){
    for (int i = 1; i < 4; i++) m = fmaxf(m, ws_[i]);
    atomicMax(redmax, fkey(m));
  }
}

__global__ __launch_bounds__(256) void k_smax_sum(const float* __restrict__ scores,
                                                  const unsigned* __restrict__ redmax,
                                                  float* __restrict__ redsum){
  float mx = funkey(*redmax);
  float s = 0.f;
  for (int i = blockIdx.x * blockDim.x + threadIdx.x; i < N_NODESC;
       i += gridDim.x * blockDim.x)
    s += expf(scores[i] - mx);
  s = wave_sum(s);
  __shared__ float ws_[4];
  int lane = threadIdx.x & 63, w = threadIdx.x >> 6;
  if (lane == 0) ws_[w] = s;
  __syncthreads();
  if (threadIdx.x == 0){
    float t = 0.f;
    for (int i = 0; i < 4; i++) t += ws_[i];
    atomicAdd(redsum, t);
  }
}

__global__ __launch_bounds__(256) void k_smax_write(const float* __restrict__ scores,
                                                    const unsigned* __restrict__ redmax,
                                                    const float* __restrict__ redsum,
                                                    float* __restrict__ out){
  int i = blockIdx.x * blockDim.x + threadIdx.x;
  if (i >= N_NODESC) return;
  float mx = funkey(*redmax);
  float inv = 1.0f / (*redsum);
  out[i] = expf(scores[i] - mx) * inv;
}

extern "C" void kernel_launch(void* const* d_in, const int* in_sizes, int n_in,
                              void* d_out, int out_size, void* d_ws, size_t ws_size,
                              hipStream_t stream) {
  const float* x    = (const float*)d_in[0];
  const float* ea   = (const float*)d_in[1];
  const float* W1l  = (const float*)d_in[2];
  const float* W1r  = (const float*)d_in[3];
  const float* W1e  = (const float*)d_in[4];
  const float* att1 = (const float*)d_in[5];
  const float* b1   = (const float*)d_in[6];
  const float* W2l  = (const float*)d_in[7];
  const float* W2r  = (const float*)d_in[8];
  const float* W2e  = (const float*)d_in[9];
  const float* att2 = (const float*)d_in[10];
  const float* b2   = (const float*)d_in[11];
  const int*   ei   = (const int*)d_in[12];
  float* out = (float*)d_out;

  char* w = (char*)d_ws;
  size_t off = 0;
  auto alloc = [&](size_t bytes) -> char* {
    char* p = w + off;
    off = (off + bytes + 255) & ~(size_t)255;
    return p;
  };
  // ---- zero zone (memset every call) ----
  float*    meanacc = (float*)alloc(16);
  unsigned* redmax  = (unsigned*)alloc(8);
  float*    redsum  = (float*)((char*)redmax + 4);
  int*      deg     = (int*)alloc((size_t)N_NODESC * 4);
  size_t zero_bytes = off;
  // ---- rest ----
  int*   offsets = (int*)alloc((size_t)(N_NODESC + 1) * 4);
  int*   cursor  = (int*)alloc((size_t)N_NODESC * 4);
  int*   perm    = (int*)alloc((size_t)E_TOTC * 4);
  int*   srcp    = (int*)alloc((size_t)E_TOTC * 4);
  float* logits1 = (float*)alloc((size_t)E_TOTC * 4 * 4);
  float* lg2     = (float*)alloc((size_t)E_TOTC * 4);
  float* sl      = (float*)alloc((size_t)N_NODESC * 4);
  float* sr      = (float*)alloc((size_t)N_NODESC * 4);
  float* scores  = (float*)alloc((size_t)N_NODESC * 4);
  float* xl      = (float*)alloc((size_t)N_NODESC * FDIM * 4);
  float* xr      = (float*)alloc((size_t)N_NODESC * FDIM * 4);
  (void)ws_size; (void)in_sizes; (void)n_in; (void)out_size;

  hipMemsetAsync(d_ws, 0, zero_bytes, stream);

  k_mean  <<<400, 256, 0, stream>>>(ea, meanacc);
  k_gemm1 <<<N_NODESC / 8, 256, 0, stream>>>(x, W1l, W1r, xl, xr);
  k_count <<<(E_TOTC + 255) / 256, 256, 0, stream>>>(ei, deg);
  k_scan  <<<1, 1024, 0, stream>>>(deg, offsets, cursor);
  k_scatter<<<(E_TOTC + 255) / 256, 256, 0, stream>>>(ei, cursor, perm);
  k_logits1<<<E_TOTC / 4, 256, 0, stream>>>(ei, ea, W1e, att1, meanacc, perm,
                                            xl, xr, logits1, srcp);
  k_node1 <<<N_NODESC, 256, 0, stream>>>(offsets, srcp, logits1, xl, b1,
                                         W2l, W2r, sl, sr);
  k_logits2<<<(E_TOTC + 255) / 256, 256, 0, stream>>>(ei, ea, W2e, att2, meanacc,
                                                      perm, srcp, sl, sr, lg2);
  k_node2 <<<(N_NODESC + 3) / 4, 256, 0, stream>>>(offsets, srcp, lg2, sl, b2,
                                                   scores, out);
  k_smax_max <<<256, 256, 0, stream>>>(scores, redmax);
  k_smax_sum <<<256, 256, 0, stream>>>(scores, redmax, redsum);
  k_smax_write<<<(N_NODESC + 255) / 256, 256, 0, stream>>>(scores, redmax, redsum, out);
}

// Round 3
// 866.808 us; speedup vs baseline: 1.2532x; 1.2532x over previous
//
#include <hip/hip_runtime.h>
#include <hip/hip_bf16.h>

typedef __hip_bfloat16 bf16;

#define N_NODESC 50000
#define N_EDGESC 800000
#define E_TOTC   850000   // + self loops
#define IN_DIMC  128
#define FDIM     256      // HEADS*HID
#define HEADSC   4
#define HIDC     64
#define NEG_SLOPE 0.2f

__device__ __forceinline__ float wave_sum(float v){
  #pragma unroll
  for (int m = 32; m > 0; m >>= 1) v += __shfl_xor(v, m, 64);
  return v;
}
__device__ __forceinline__ float wave_max(float v){
  #pragma unroll
  for (int m = 32; m > 0; m >>= 1) v = fmaxf(v, __shfl_xor(v, m, 64));
  return v;
}

// ---------- edge_attr column means (for self-loop fill) ----------
__global__ __launch_bounds__(256) void k_mean(const float* __restrict__ ea,
                                              float* __restrict__ meanacc){
  float s0 = 0.f, s1 = 0.f, s2 = 0.f;
  for (int i = blockIdx.x * blockDim.x + threadIdx.x; i < N_EDGESC;
       i += gridDim.x * blockDim.x){
    s0 += ea[i*3+0]; s1 += ea[i*3+1]; s2 += ea[i*3+2];
  }
  s0 = wave_sum(s0); s1 = wave_sum(s1); s2 = wave_sum(s2);
  __shared__ float red[3][4];
  int lane = threadIdx.x & 63, w = threadIdx.x >> 6;
  if (lane == 0){ red[0][w] = s0; red[1][w] = s1; red[2][w] = s2; }
  __syncthreads();
  if (threadIdx.x == 0){
    float t0 = 0.f, t1 = 0.f, t2 = 0.f;
    for (int i = 0; i < 4; i++){ t0 += red[0][i]; t1 += red[1][i]; t2 += red[2][i]; }
    atomicAdd(&meanacc[0], t0); atomicAdd(&meanacc[1], t1); atomicAdd(&meanacc[2], t2);
  }
}

// ---------- layer-1 dual GEMM: xl = x@W1l, xr = x@W1r (bf16 out) ----------
__global__ __launch_bounds__(256) void k_gemm1(const float* __restrict__ x,
                                               const float* __restrict__ Wl,
                                               const float* __restrict__ Wr,
                                               bf16* __restrict__ xl,
                                               bf16* __restrict__ xr){
  __shared__ float xs[8][IN_DIMC];
  const int r0 = blockIdx.x * 8;
  const int t = threadIdx.x;
  for (int i = t; i < 8 * IN_DIMC; i += 256){
    int r = i >> 7, k = i & 127;
    xs[r][k] = x[(size_t)(r0 + r) * IN_DIMC + k];
  }
  __syncthreads();
  float accl[8] = {0,0,0,0,0,0,0,0};
  float accr[8] = {0,0,0,0,0,0,0,0};
  for (int k = 0; k < IN_DIMC; k++){
    float wl = Wl[k * FDIM + t];
    float wr = Wr[k * FDIM + t];
    #pragma unroll
    for (int r = 0; r < 8; r++){ accl[r] += xs[r][k] * wl; accr[r] += xs[r][k] * wr; }
  }
  #pragma unroll
  for (int r = 0; r < 8; r++){
    xl[(size_t)(r0 + r) * FDIM + t] = __float2bfloat16(accl[r]);
    xr[(size_t)(r0 + r) * FDIM + t] = __float2bfloat16(accr[r]);
  }
}

// ---------- CSR build: count, scan, scatter ----------
__global__ __launch_bounds__(256) void k_count(const int* __restrict__ ei,
                                               int* __restrict__ deg){
  int e = blockIdx.x * blockDim.x + threadIdx.x;
  if (e >= E_TOTC) return;
  int dst = (e < N_EDGESC) ? ei[N_EDGESC + e] : (e - N_EDGESC);
  atomicAdd(&deg[dst], 1);
}

__global__ __launch_bounds__(1024) void k_scan(const int* __restrict__ deg,
                                               int* __restrict__ offsets,
                                               int* __restrict__ cursor){
  const int n = N_NODESC;
  const int T = 1024;
  const int CH = (n + T - 1) / T;
  int t = threadIdx.x;
  int beg = t * CH, end = min(beg + CH, n);
  int s = 0;
  for (int i = beg; i < end; i++) s += deg[i];
  __shared__ int sums[1024];
  sums[t] = s;
  __syncthreads();
  for (int off = 1; off < T; off <<= 1){
    int v = (t >= off) ? sums[t - off] : 0;
    __syncthreads();
    sums[t] += v;
    __syncthreads();
  }
  int run = sums[t] - s;             // exclusive prefix
  for (int i = beg; i < end; i++){
    offsets[i] = run; cursor[i] = run; run += deg[i];
  }
  if (t == T - 1) offsets[n] = sums[T - 1];
}

__global__ __launch_bounds__(256) void k_scatter(const int* __restrict__ ei,
                                                 int* __restrict__ cursor,
                                                 int* __restrict__ perm,
                                                 int* __restrict__ srcp){
  int e = blockIdx.x * blockDim.x + threadIdx.x;
  if (e >= E_TOTC) return;
  int src, dst;
  if (e < N_EDGESC){ src = ei[e]; dst = ei[N_EDGESC + e]; }
  else             { src = dst = e - N_EDGESC; }
  int pos = atomicAdd(&cursor[dst], 1);
  perm[pos] = e;
  srcp[pos] = src;
}

// ---------- layer-1 FUSED: online segment softmax + aggregation + ELU + layer-2 dots
// one block per node; wave w owns head w: per-head (m, den, acc) live in registers,
// no LDS / no syncthreads in the edge loop.
__global__ __launch_bounds__(256) void k_attn1(const int* __restrict__ offsets,
                                               const int* __restrict__ srcp,
                                               const int* __restrict__ perm,
                                               const float* __restrict__ ea,
                                               const float* __restrict__ meanacc,
                                               const bf16* __restrict__ xl,
                                               const bf16* __restrict__ xr,
                                               const float* __restrict__ W1e,
                                               const float* __restrict__ att1,
                                               const float* __restrict__ b1,
                                               const float* __restrict__ W2l,
                                               const float* __restrict__ W2r,
                                               float* __restrict__ sl,
                                               float* __restrict__ sr){
  const int n = blockIdx.x;
  const int t = threadIdx.x, lane = t & 63, w = t >> 6;
  // per-feature constants (feature index == t)
  const float we0 = W1e[t], we1 = W1e[FDIM + t], we2 = W1e[2*FDIM + t];
  const float attv = att1[t];
  const float xrv = __bfloat162float(xr[(size_t)n * FDIM + t]);
  const float inv = 1.0f / (float)N_EDGESC;
  const float me0 = meanacc[0]*inv, me1 = meanacc[1]*inv, me2 = meanacc[2]*inv;
  const int beg = offsets[n], end = offsets[n + 1];

  float m = -1e30f, den = 0.f, acc = 0.f;
  for (int j = beg; j < end; j++){
    int src = srcp[j];
    int e   = perm[j];
    float e0, e1, e2;
    if (e < N_EDGESC){ e0 = ea[e*3+0]; e1 = ea[e*3+1]; e2 = ea[e*3+2]; }
    else             { e0 = me0; e1 = me1; e2 = me2; }
    float xlv = __bfloat162float(xl[(size_t)src * FDIM + t]);
    float v = xlv + xrv + e0*we0 + e1*we1 + e2*we2;
    v = (v > 0.f) ? v : NEG_SLOPE * v;
    float p = wave_sum(v * attv);          // logit of head w (all lanes hold it)
    float mn = fmaxf(m, p);
    float corr = __expf(m - mn);           // m=-1e30 first iter -> 0
    float pe   = __expf(p - mn);
    den = den * corr + pe;
    acc = acc * corr + pe * xlv;
    m = mn;
  }
  float h = acc / den + b1[t];
  h = (h > 0.f) ? h : (__expf(h) - 1.f);   // ELU
  // fused layer-2 per-node dots
  float a = wave_sum(h * W2l[t]);
  float b = wave_sum(h * W2r[t]);
  __shared__ float sred[2][4];
  if (lane == 0){ sred[0][w] = a; sred[1][w] = b; }
  __syncthreads();
  if (t == 0){
    sl[n] = sred[0][0] + sred[0][1] + sred[0][2] + sred[0][3];
    sr[n] = sred[1][0] + sred[1][1] + sred[1][2] + sred[1][3];
  }
}

// ---------- layer-2 FUSED: edge logits + online softmax + aggregate -> scores
// one wave per node; lanes stride the node's edge list, online per-lane state,
// exact wave-combine at the end.
__global__ __launch_bounds__(256) void k_attn2(const int* __restrict__ offsets,
                                               const int* __restrict__ srcp,
                                               const int* __restrict__ perm,
                                               const float* __restrict__ ea,
                                               const float* __restrict__ meanacc,
                                               const float* __restrict__ W2e,
                                               const float* __restrict__ att2,
                                               const float* __restrict__ b2p,
                                               const float* __restrict__ sl,
                                               const float* __restrict__ sr,
                                               float* __restrict__ scores,
                                               float* __restrict__ out){
  int t = threadIdx.x, lane = t & 63;
  int n = blockIdx.x * 4 + (t >> 6);
  if (n >= N_NODESC) return;
  const float w0 = W2e[0], w1 = W2e[1], w2 = W2e[2], attv = att2[0];
  const float inv = 1.0f / (float)N_EDGESC;
  const float me0 = meanacc[0]*inv, me1 = meanacc[1]*inv, me2 = meanacc[2]*inv;
  const float srn = sr[n];
  int beg = offsets[n], end = offsets[n + 1];
  float m = -1e30f, den = 0.f, num = 0.f;
  for (int j = beg + lane; j < end; j += 64){
    int e = perm[j];
    float e0, e1, e2;
    if (e < N_EDGESC){ e0 = ea[e*3+0]; e1 = ea[e*3+1]; e2 = ea[e*3+2]; }
    else             { e0 = me0; e1 = me1; e2 = me2; }
    float slv = sl[srcp[j]];
    float v = slv + srn + e0*w0 + e1*w1 + e2*w2;
    v = (v > 0.f) ? v : NEG_SLOPE * v;
    float lg = v * attv;
    float mn = fmaxf(m, lg);
    float corr = __expf(m - mn);
    float pe   = __expf(lg - mn);
    den = den * corr + pe;
    num = num * corr + pe * slv;
    m = mn;
  }
  // wave combine (exact)
  float mg = wave_max(m);
  float scale = __expf(m - mg);            // 0 for empty lanes
  float deng = wave_sum(den * scale);
  float numg = wave_sum(num * scale);
  if (lane == 0){
    float s = numg / deng + b2p[0];
    scores[n] = s;
    out[N_NODESC + n] = s;
  }
}

// ---------- global softmax over scores ----------
__device__ __forceinline__ unsigned fkey(float f){
  unsigned u = __float_as_uint(f);
  return u ^ ((u >> 31) ? 0xFFFFFFFFu : 0x80000000u);
}
__device__ __forceinline__ float funkey(unsigned k){
  unsigned u = (k >> 31) ? (k ^ 0x80000000u) : ~k;
  return __uint_as_float(u);
}

__global__ __launch_bounds__(256) void k_smax_max(const float* __restrict__ scores,
                                                  unsigned* __restrict__ redmax){
  float m = -1e30f;
  for (int i = blockIdx.x * blockDim.x + threadIdx.x; i < N_NODESC;
       i += gridDim.x * blockDim.x)
    m = fmaxf(m, scores[i]);
  m = wave_max(m);
  __shared__ float ws_[4];
  int lane = threadIdx.x & 63, w = threadIdx.x >> 6;
  if (lane == 0) ws_[w] = m;
  __syncthreads();
  if (threadIdx.x == 0){
    for (int i = 1; i < 4; i++) m = fmaxf(m, ws_[i]);
    atomicMax(redmax, fkey(m));
  }
}

__global__ __launch_bounds__(256) void k_smax_sum(const float* __restrict__ scores,
                                                  const unsigned* __restrict__ redmax,
                                                  float* __restrict__ redsum){
  float mx = funkey(*redmax);
  float s = 0.f;
  for (int i = blockIdx.x * blockDim.x + threadIdx.x; i < N_NODESC;
       i += gridDim.x * blockDim.x)
    s += __expf(scores[i] - mx);
  s = wave_sum(s);
  __shared__ float ws_[4];
  int lane = threadIdx.x & 63, w = threadIdx.x >> 6;
  if (lane == 0) ws_[w] = s;
  __syncthreads();
  if (threadIdx.x == 0){
    float t = 0.f;
    for (int i = 0; i < 4; i++) t += ws_[i];
    atomicAdd(redsum, t);
  }
}

__global__ __launch_bounds__(256) void k_smax_write(const float* __restrict__ scores,
                                                    const unsigned* __restrict__ redmax,
                                                    const float* __restrict__ redsum,
                                                    float* __restrict__ out){
  int i = blockIdx.x * blockDim.x + threadIdx.x;
  if (i >= N_NODESC) return;
  float mx = funkey(*redmax);
  float inv = 1.0f / (*redsum);
  out[i] = __expf(scores[i] - mx) * inv;
}

extern "C" void kernel_launch(void* const* d_in, const int* in_sizes, int n_in,
                              void* d_out, int out_size, void* d_ws, size_t ws_size,
                              hipStream_t stream) {
  const float* x    = (const float*)d_in[0];
  const float* ea   = (const float*)d_in[1];
  const float* W1l  = (const float*)d_in[2];
  const float* W1r  = (const float*)d_in[3];
  const float* W1e  = (const float*)d_in[4];
  const float* att1 = (const float*)d_in[5];
  const float* b1   = (const float*)d_in[6];
  const float* W2l  = (const float*)d_in[7];
  const float* W2r  = (const float*)d_in[8];
  const float* W2e  = (const float*)d_in[9];
  const float* att2 = (const float*)d_in[10];
  const float* b2   = (const float*)d_in[11];
  const int*   ei   = (const int*)d_in[12];
  float* out = (float*)d_out;

  char* w = (char*)d_ws;
  size_t off = 0;
  auto alloc = [&](size_t bytes) -> char* {
    char* p = w + off;
    off = (off + bytes + 255) & ~(size_t)255;
    return p;
  };
  // ---- zero zone (memset every call) ----
  float*    meanacc = (float*)alloc(16);
  unsigned* redmax  = (unsigned*)alloc(8);
  float*    redsum  = (float*)((char*)redmax + 4);
  int*      deg     = (int*)alloc((size_t)N_NODESC * 4);
  size_t zero_bytes = off;
  // ---- rest ----
  int*   offsets = (int*)alloc((size_t)(N_NODESC + 1) * 4);
  int*   cursor  = (int*)alloc((size_t)N_NODESC * 4);
  int*   perm    = (int*)alloc((size_t)E_TOTC * 4);
  int*   srcp    = (int*)alloc((size_t)E_TOTC * 4);
  float* sl      = (float*)alloc((size_t)N_NODESC * 4);
  float* sr      = (float*)alloc((size_t)N_NODESC * 4);
  float* scores  = (float*)alloc((size_t)N_NODESC * 4);
  bf16*  xl      = (bf16*)alloc((size_t)N_NODESC * FDIM * 2);
  bf16*  xr      = (bf16*)alloc((size_t)N_NODESC * FDIM * 2);
  (void)ws_size; (void)in_sizes; (void)n_in; (void)out_size;

  hipMemsetAsync(d_ws, 0, zero_bytes, stream);

  k_mean  <<<400, 256, 0, stream>>>(ea, meanacc);
  k_gemm1 <<<N_NODESC / 8, 256, 0, stream>>>(x, W1l, W1r, xl, xr);
  k_count <<<(E_TOTC + 255) / 256, 256, 0, stream>>>(ei, deg);
  k_scan  <<<1, 1024, 0, stream>>>(deg, offsets, cursor);
  k_scatter<<<(E_TOTC + 255) / 256, 256, 0, stream>>>(ei, cursor, perm, srcp);
  k_attn1 <<<N_NODESC, 256, 0, stream>>>(offsets, srcp, perm, ea, meanacc,
                                         xl, xr, W1e, att1, b1, W2l, W2r, sl, sr);
  k_attn2 <<<(N_NODESC + 3) / 4, 256, 0, stream>>>(offsets, srcp, perm, ea, meanacc,
                                                   W2e, att2, b2, sl, sr, scores, out);
  k_smax_max <<<256, 256, 0, stream>>>(scores, redmax);
  k_smax_sum <<<256, 256, 0, stream>>>(scores, redmax, redsum);
  k_smax_write<<<(N_NODESC + 255) / 256, 256, 0, stream>>>(scores, redmax, redsum, out);
}

// Round 4
// 612.481 us; speedup vs baseline: 1.7736x; 1.4152x over previous
//
#include <hip/hip_runtime.h>
#include <hip/hip_bf16.h>

typedef __hip_bfloat16 bf16;
typedef __attribute__((ext_vector_type(8))) short short8;
typedef __attribute__((ext_vector_type(4))) float floatx4;
typedef __attribute__((ext_vector_type(4))) unsigned short ushortx4;

#define N_NODESC 50000
#define MPAD     50016     // padded to 32-row tiles
#define N_EDGESC 800000
#define E_TOTC   850000    // + self loops
#define IN_DIMC  128
#define FDIM     256       // HEADS*HID
#define HEADSC   4
#define HIDC     64
#define NEG_SLOPE 0.2f
#define CHUNK    32

__device__ __forceinline__ float bits2f(unsigned short b){
  return __uint_as_float(((unsigned)b) << 16);
}

__device__ __forceinline__ float wave_sum(float v){
  #pragma unroll
  for (int m = 32; m > 0; m >>= 1) v += __shfl_xor(v, m, 64);
  return v;
}
__device__ __forceinline__ float wave_max(float v){
  #pragma unroll
  for (int m = 32; m > 0; m >>= 1) v = fmaxf(v, __shfl_xor(v, m, 64));
  return v;
}

// ---------- edge_attr column means (for self-loop fill) ----------
__global__ __launch_bounds__(256) void k_mean(const float* __restrict__ ea,
                                              float* __restrict__ meanacc){
  float s0 = 0.f, s1 = 0.f, s2 = 0.f;
  for (int i = blockIdx.x * blockDim.x + threadIdx.x; i < N_EDGESC;
       i += gridDim.x * blockDim.x){
    s0 += ea[i*3+0]; s1 += ea[i*3+1]; s2 += ea[i*3+2];
  }
  s0 = wave_sum(s0); s1 = wave_sum(s1); s2 = wave_sum(s2);
  __shared__ float red[3][4];
  int lane = threadIdx.x & 63, w = threadIdx.x >> 6;
  if (lane == 0){ red[0][w] = s0; red[1][w] = s1; red[2][w] = s2; }
  __syncthreads();
  if (threadIdx.x == 0){
    float t0 = 0.f, t1 = 0.f, t2 = 0.f;
    for (int i = 0; i < 4; i++){ t0 += red[0][i]; t1 += red[1][i]; t2 += red[2][i]; }
    atomicAdd(&meanacc[0], t0); atomicAdd(&meanacc[1], t1); atomicAdd(&meanacc[2], t2);
  }
}

// ---------- convert x (fp32) -> xb (bf16 bits), zero pad rows ----------
__global__ __launch_bounds__(256) void k_cvtx(const float* __restrict__ x,
                                              unsigned short* __restrict__ xb){
  size_t tid = (size_t)blockIdx.x * 256 + threadIdx.x;
  size_t base = tid * 4;
  const size_t NELEM = (size_t)N_NODESC * IN_DIMC;   // 6,400,000
  ushortx4 o;
  if (base + 3 < NELEM){
    const float4* xp = (const float4*)(x + base);
    float4 v = *xp;
    o[0] = (unsigned short)(__float_as_uint(v.x) >> 16);
    o[1] = (unsigned short)(__float_as_uint(v.y) >> 16);
    o[2] = (unsigned short)(__float_as_uint(v.z) >> 16);
    o[3] = (unsigned short)(__float_as_uint(v.w) >> 16);
  } else {
    #pragma unroll
    for (int f = 0; f < 4; f++){
      size_t i = base + f;
      float v = (i < NELEM) ? x[i] : 0.f;
      o[f] = (unsigned short)(__float_as_uint(v) >> 16);
    }
  }
  *(ushortx4*)(xb + base) = o;
}

// ---------- convert W1l,W1r -> MFMA-frag-contiguous bf16 layout ----------
// out[mat][kblk(16)][n(256)][j(8)] = W[kblk*8+j][n]
__global__ __launch_bounds__(256) void k_cvtw(const float* __restrict__ W1l,
                                              const float* __restrict__ W1r,
                                              unsigned short* __restrict__ Bfrag){
  int idx = blockIdx.x * 256 + threadIdx.x;   // < 65536
  int mat = idx >> 15;
  int r   = idx & 32767;       // k*256+n
  int k   = r >> 8, n = r & 255;
  float v = mat ? W1r[r] : W1l[r];
  int pos = (mat << 15) + (((k >> 3) << 8) + n) * 8 + (k & 7);
  Bfrag[pos] = (unsigned short)(__float_as_uint(v) >> 16);
}

// ---------- MFMA dual GEMM: xl = x@W1l, xr = x@W1r (bf16 out) ----------
__global__ __launch_bounds__(256) void k_gemm_mfma(const unsigned short* __restrict__ xb,
                                                   const unsigned short* __restrict__ Bfrag,
                                                   unsigned short* __restrict__ xl,
                                                   unsigned short* __restrict__ xr){
  const int mat = blockIdx.y;
  const int r0  = blockIdx.x * 32;
  const int w = threadIdx.x >> 6, lane = threadIdx.x & 63;
  const int quad = lane >> 4, l16 = lane & 15;
  const unsigned short* Bm = Bfrag + ((size_t)mat << 15);
  unsigned short* C = mat ? xr : xl;

  short8 afr[2][4];
  #pragma unroll
  for (int ms = 0; ms < 2; ms++)
    #pragma unroll
    for (int ks = 0; ks < 4; ks++){
      const unsigned short* p = xb + (size_t)(r0 + ms*16 + l16) * IN_DIMC + ks*32 + quad*8;
      afr[ms][ks] = *reinterpret_cast<const short8*>(p);
    }
  const int n0 = w * 64;
  floatx4 acc[2][4];
  #pragma unroll
  for (int ms = 0; ms < 2; ms++)
    #pragma unroll
    for (int ns = 0; ns < 4; ns++){
      floatx4 z = {0.f, 0.f, 0.f, 0.f};
      acc[ms][ns] = z;
    }
  #pragma unroll
  for (int ks = 0; ks < 4; ks++){
    #pragma unroll
    for (int ns = 0; ns < 4; ns++){
      int n = n0 + ns*16 + l16;
      int kblk = ks*4 + quad;
      short8 bfr = *reinterpret_cast<const short8*>(Bm + ((size_t)kblk*256 + n)*8);
      acc[0][ns] = __builtin_amdgcn_mfma_f32_16x16x32_bf16(afr[0][ks], bfr, acc[0][ns], 0, 0, 0);
      acc[1][ns] = __builtin_amdgcn_mfma_f32_16x16x32_bf16(afr[1][ks], bfr, acc[1][ns], 0, 0, 0);
    }
  }
  #pragma unroll
  for (int ms = 0; ms < 2; ms++)
    #pragma unroll
    for (int ns = 0; ns < 4; ns++){
      int col = n0 + ns*16 + l16;
      #pragma unroll
      for (int rg = 0; rg < 4; rg++){
        int row = r0 + ms*16 + quad*4 + rg;
        C[(size_t)row * FDIM + col] = (unsigned short)(__float_as_uint(acc[ms][ns][rg]) >> 16);
      }
    }
}

// ---------- CSR build: count, scan, scatter(+edge-attr pre-gather) ----------
__global__ __launch_bounds__(256) void k_count(const int* __restrict__ ei,
                                               int* __restrict__ deg){
  int e = blockIdx.x * blockDim.x + threadIdx.x;
  if (e >= E_TOTC) return;
  int dst = (e < N_EDGESC) ? ei[N_EDGESC + e] : (e - N_EDGESC);
  atomicAdd(&deg[dst], 1);
}

__global__ __launch_bounds__(1024) void k_scan(const int* __restrict__ deg,
                                               int* __restrict__ offsets,
                                               int* __restrict__ cursor){
  const int n = N_NODESC;
  const int T = 1024;
  const int CH = (n + T - 1) / T;
  int t = threadIdx.x;
  int beg = t * CH, end = min(beg + CH, n);
  int s = 0;
  for (int i = beg; i < end; i++) s += deg[i];
  __shared__ int sums[1024];
  sums[t] = s;
  __syncthreads();
  for (int off = 1; off < T; off <<= 1){
    int v = (t >= off) ? sums[t - off] : 0;
    __syncthreads();
    sums[t] += v;
    __syncthreads();
  }
  int run = sums[t] - s;
  for (int i = beg; i < end; i++){
    offsets[i] = run; cursor[i] = run; run += deg[i];
  }
  if (t == T - 1) offsets[n] = sums[T - 1];
}

__global__ __launch_bounds__(256) void k_scatter(const int* __restrict__ ei,
                                                 const float* __restrict__ ea,
                                                 const float* __restrict__ meanacc,
                                                 const float* __restrict__ W2e,
                                                 int* __restrict__ cursor,
                                                 int* __restrict__ srcp,
                                                 float* __restrict__ eap,
                                                 float* __restrict__ ef2){
  int e = blockIdx.x * blockDim.x + threadIdx.x;
  if (e >= E_TOTC) return;
  int src, dst; float e0, e1, e2;
  if (e < N_EDGESC){
    src = ei[e]; dst = ei[N_EDGESC + e];
    e0 = ea[e*3+0]; e1 = ea[e*3+1]; e2 = ea[e*3+2];
  } else {
    src = dst = e - N_EDGESC;
    const float inv = 1.0f / (float)N_EDGESC;
    e0 = meanacc[0]*inv; e1 = meanacc[1]*inv; e2 = meanacc[2]*inv;
  }
  int pos = atomicAdd(&cursor[dst], 1);
  srcp[pos] = src;
  eap[pos*3+0] = e0; eap[pos*3+1] = e1; eap[pos*3+2] = e2;
  ef2[pos] = e0*W2e[0] + e1*W2e[1] + e2*W2e[2];
}

// ---------- layer-1 FUSED, chunked two-phase ----------
// phase A: waves own edges (parallel gather + segmented 16-lane logit reduce)
// phase B: 256 threads do online-softmax accumulation from LDS-staged rows.
__global__ __launch_bounds__(256) void k_attn1(const int* __restrict__ offsets,
                                               const int* __restrict__ srcp,
                                               const float* __restrict__ eap,
                                               const unsigned short* __restrict__ xl,
                                               const unsigned short* __restrict__ xr,
                                               const float* __restrict__ W1e,
                                               const float* __restrict__ att1,
                                               const float* __restrict__ b1,
                                               const float* __restrict__ W2l,
                                               const float* __restrict__ W2r,
                                               float* __restrict__ sl,
                                               float* __restrict__ sr){
  const int n = blockIdx.x;
  const int t = threadIdx.x, lane = t & 63, w = t >> 6;
  __shared__ float w1e_s[3*FDIM];
  __shared__ float att_s[FDIM];
  __shared__ float xr_s[FDIM];
  __shared__ unsigned short xls[CHUNK][FDIM];
  __shared__ float lgs[HEADSC][CHUNK];
  w1e_s[t] = W1e[t]; w1e_s[FDIM+t] = W1e[FDIM+t]; w1e_s[2*FDIM+t] = W1e[2*FDIM+t];
  att_s[t] = att1[t];
  xr_s[t]  = bits2f(xr[(size_t)n * FDIM + t]);
  __syncthreads();
  const int beg = offsets[n], end = offsets[n + 1];
  float m = -1e30f, den = 0.f, acc = 0.f;
  const int f0 = lane * 4;
  for (int c0 = beg; c0 < end; c0 += CHUNK){
    int cnt = min(CHUNK, end - c0);
    // ---- phase A ----
    for (int i = w; i < cnt; i += 4){
      int j = c0 + i;
      int src = srcp[j];
      float e0 = eap[j*3+0], e1 = eap[j*3+1], e2 = eap[j*3+2];
      ushortx4 raw = *(const ushortx4*)(xl + (size_t)src * FDIM + f0);
      float pp = 0.f;
      #pragma unroll
      for (int f = 0; f < 4; f++){
        int ft = f0 + f;
        float v = bits2f(raw[f]) + xr_s[ft]
                + e0*w1e_s[ft] + e1*w1e_s[FDIM+ft] + e2*w1e_s[2*FDIM+ft];
        v = (v > 0.f) ? v : NEG_SLOPE * v;
        pp += v * att_s[ft];
      }
      pp += __shfl_xor(pp, 1, 64);
      pp += __shfl_xor(pp, 2, 64);
      pp += __shfl_xor(pp, 4, 64);
      pp += __shfl_xor(pp, 8, 64);
      if ((lane & 15) == 0) lgs[lane >> 4][i] = pp;
      *(ushortx4*)&xls[i][f0] = raw;
    }
    __syncthreads();
    // ---- phase B ----
    float cm = -1e30f;
    for (int i = 0; i < cnt; i++) cm = fmaxf(cm, lgs[w][i]);
    float mn = fmaxf(m, cm);
    float corr = __expf(m - mn);
    den *= corr; acc *= corr;
    for (int i = 0; i < cnt; i++){
      float al = __expf(lgs[w][i] - mn);
      den += al;
      acc += al * bits2f(xls[i][t]);
    }
    m = mn;
    __syncthreads();
  }
  float h = acc / den + b1[t];
  h = (h > 0.f) ? h : (__expf(h) - 1.f);   // ELU
  float a = wave_sum(h * W2l[t]);
  float b = wave_sum(h * W2r[t]);
  __shared__ float sred[2][4];
  if (lane == 0){ sred[0][w] = a; sred[1][w] = b; }
  __syncthreads();
  if (t == 0){
    sl[n] = sred[0][0] + sred[0][1] + sred[0][2] + sred[0][3];
    sr[n] = sred[1][0] + sred[1][1] + sred[1][2] + sred[1][3];
  }
}

// ---------- layer-2 FUSED: edge logits + online softmax -> scores ----------
__global__ __launch_bounds__(256) void k_attn2(const int* __restrict__ offsets,
                                               const int* __restrict__ srcp,
                                               const float* __restrict__ ef2,
                                               const float* __restrict__ att2,
                                               const float* __restrict__ b2p,
                                               const float* __restrict__ sl,
                                               const float* __restrict__ sr,
                                               float* __restrict__ scores,
                                               float* __restrict__ out){
  int t = threadIdx.x, lane = t & 63;
  int n = blockIdx.x * 4 + (t >> 6);
  if (n >= N_NODESC) return;
  const float attv = att2[0];
  const float srn = sr[n];
  int beg = offsets[n], end = offsets[n + 1];
  float m = -1e30f, den = 0.f, num = 0.f;
  for (int j = beg + lane; j < end; j += 64){
    float slv = sl[srcp[j]];
    float v = slv + srn + ef2[j];
    v = (v > 0.f) ? v : NEG_SLOPE * v;
    float lg = v * attv;
    float mn = fmaxf(m, lg);
    float corr = __expf(m - mn);
    float pe   = __expf(lg - mn);
    den = den * corr + pe;
    num = num * corr + pe * slv;
    m = mn;
  }
  float mg = wave_max(m);
  float scale = __expf(m - mg);
  float deng = wave_sum(den * scale);
  float numg = wave_sum(num * scale);
  if (lane == 0){
    float s = numg / deng + b2p[0];
    scores[n] = s;
    out[N_NODESC + n] = s;
  }
}

// ---------- global softmax over scores ----------
__device__ __forceinline__ unsigned fkey(float f){
  unsigned u = __float_as_uint(f);
  return u ^ ((u >> 31) ? 0xFFFFFFFFu : 0x80000000u);
}
__device__ __forceinline__ float funkey(unsigned k){
  unsigned u = (k >> 31) ? (k ^ 0x80000000u) : ~k;
  return __uint_as_float(u);
}

__global__ __launch_bounds__(256) void k_smax_max(const float* __restrict__ scores,
                                                  unsigned* __restrict__ redmax){
  float m = -1e30f;
  for (int i = blockIdx.x * blockDim.x + threadIdx.x; i < N_NODESC;
       i += gridDim.x * blockDim.x)
    m = fmaxf(m, scores[i]);
  m = wave_max(m);
  __shared__ float ws_[4];
  int lane = threadIdx.x & 63, w = threadIdx.x >> 6;
  if (lane == 0) ws_[w] = m;
  __syncthreads();
  if (threadIdx.x == 0){
    for (int i = 1; i < 4; i++) m = fmaxf(m, ws_[i]);
    atomicMax(redmax, fkey(m));
  }
}

__global__ __launch_bounds__(256) void k_smax_sum(const float* __restrict__ scores,
                                                  const unsigned* __restrict__ redmax,
                                                  float* __restrict__ redsum){
  float mx = funkey(*redmax);
  float s = 0.f;
  for (int i = blockIdx.x * blockDim.x + threadIdx.x; i < N_NODESC;
       i += gridDim.x * blockDim.x)
    s += __expf(scores[i] - mx);
  s = wave_sum(s);
  __shared__ float ws_[4];
  int lane = threadIdx.x & 63, w = threadIdx.x >> 6;
  if (lane == 0) ws_[w] = s;
  __syncthreads();
  if (threadIdx.x == 0){
    float t = 0.f;
    for (int i = 0; i < 4; i++) t += ws_[i];
    atomicAdd(redsum, t);
  }
}

__global__ __launch_bounds__(256) void k_smax_write(const float* __restrict__ scores,
                                                    const unsigned* __restrict__ redmax,
                                                    const float* __restrict__ redsum,
                                                    float* __restrict__ out){
  int i = blockIdx.x * blockDim.x + threadIdx.x;
  if (i >= N_NODESC) return;
  float mx = funkey(*redmax);
  float inv = 1.0f / (*redsum);
  out[i] = __expf(scores[i] - mx) * inv;
}

extern "C" void kernel_launch(void* const* d_in, const int* in_sizes, int n_in,
                              void* d_out, int out_size, void* d_ws, size_t ws_size,
                              hipStream_t stream) {
  const float* x    = (const float*)d_in[0];
  const float* ea   = (const float*)d_in[1];
  const float* W1l  = (const float*)d_in[2];
  const float* W1r  = (const float*)d_in[3];
  const float* W1e  = (const float*)d_in[4];
  const float* att1 = (const float*)d_in[5];
  const float* b1   = (const float*)d_in[6];
  const float* W2l  = (const float*)d_in[7];
  const float* W2r  = (const float*)d_in[8];
  const float* W2e  = (const float*)d_in[9];
  const float* att2 = (const float*)d_in[10];
  const float* b2   = (const float*)d_in[11];
  const int*   ei   = (const int*)d_in[12];
  float* out = (float*)d_out;

  char* w = (char*)d_ws;
  size_t off = 0;
  auto alloc = [&](size_t bytes) -> char* {
    char* p = w + off;
    off = (off + bytes + 255) & ~(size_t)255;
    return p;
  };
  // ---- zero zone (memset every call) ----
  float*    meanacc = (float*)alloc(16);
  unsigned* redmax  = (unsigned*)alloc(8);
  float*    redsum  = (float*)((char*)redmax + 4);
  int*      deg     = (int*)alloc((size_t)N_NODESC * 4);
  size_t zero_bytes = off;
  // ---- rest ----
  int*   offsets = (int*)alloc((size_t)(N_NODESC + 1) * 4);
  int*   cursor  = (int*)alloc((size_t)N_NODESC * 4);
  int*   srcp    = (int*)alloc((size_t)E_TOTC * 4);
  float* eap     = (float*)alloc((size_t)E_TOTC * 12);
  float* ef2     = (float*)alloc((size_t)E_TOTC * 4);
  float* sl      = (float*)alloc((size_t)N_NODESC * 4);
  float* sr      = (float*)alloc((size_t)N_NODESC * 4);
  float* scores  = (float*)alloc((size_t)N_NODESC * 4);
  unsigned short* xb    = (unsigned short*)alloc((size_t)MPAD * IN_DIMC * 2);
  unsigned short* Bfrag = (unsigned short*)alloc((size_t)2 * 128 * 256 * 2);
  unsigned short* xl    = (unsigned short*)alloc((size_t)MPAD * FDIM * 2);
  unsigned short* xr    = (unsigned short*)alloc((size_t)MPAD * FDIM * 2);
  (void)ws_size; (void)in_sizes; (void)n_in; (void)out_size;

  hipMemsetAsync(d_ws, 0, zero_bytes, stream);

  k_mean  <<<400, 256, 0, stream>>>(ea, meanacc);
  k_cvtx  <<<(int)(((size_t)MPAD * IN_DIMC / 4 + 255) / 256), 256, 0, stream>>>(x, xb);
  k_cvtw  <<<256, 256, 0, stream>>>(W1l, W1r, Bfrag);
  k_count <<<(E_TOTC + 255) / 256, 256, 0, stream>>>(ei, deg);
  k_scan  <<<1, 1024, 0, stream>>>(deg, offsets, cursor);
  k_scatter<<<(E_TOTC + 255) / 256, 256, 0, stream>>>(ei, ea, meanacc, W2e,
                                                      cursor, srcp, eap, ef2);
  {
    dim3 g(MPAD / 32, 2);
    k_gemm_mfma<<<g, 256, 0, stream>>>(xb, Bfrag, xl, xr);
  }
  k_attn1 <<<N_NODESC, 256, 0, stream>>>(offsets, srcp, eap, xl, xr,
                                         W1e, att1, b1, W2l, W2r, sl, sr);
  k_attn2 <<<(N_NODESC + 3) / 4, 256, 0, stream>>>(offsets, srcp, ef2, att2, b2,
                                                   sl, sr, scores, out);
  k_smax_max <<<256, 256, 0, stream>>>(scores, redmax);
  k_smax_sum <<<256, 256, 0, stream>>>(scores, redmax, redsum);
  k_smax_write<<<(N_NODESC + 255) / 256, 256, 0, stream>>>(scores, redmax, redsum, out);
}